// Round 6
// baseline (189.556 us; speedup 1.0000x reference)
//
#include <hip/hip_runtime.h>

#define BB 16      // batch
#define SS 48      // seq len
#define VV 16000   // vocab
#define DD 128     // embed
#define NC (DD / 4)       // 32 float4 chunks per row — ALL loops derive from this
#define TV 64             // vocab rows staged per block tile (32 KB)
#define NT 256            // threads per block
#define CPL (NC / 4)      // 8 chunks per lane (chunk-quarter)

constexpr float EPS   = 1e-8f;
constexpr float SCALE = 10.0f;

// Kernel 1: per-batch causal prefix context, normalized. One block = one batch
// element, 64 threads (lane owns d=lane and d=lane+64). ctx_n layout [S][B][D].
__global__ __launch_bounds__(64) void ctx_kernel(
    const int*   __restrict__ tokens,   // [B,S]
    const float* __restrict__ scalars,  // [S,V]
    const float* __restrict__ wvecs,    // [S,V,D]
    float*       __restrict__ ctx_n)    // [S,B,D]
{
    const int b    = blockIdx.x;
    const int lane = threadIdx.x;  // 0..63

    float a[SS], w0[SS], w1[SS];
    #pragma unroll
    for (int s = 0; s < SS; ++s) {
        const int tok = tokens[b * SS + s];
        a[s] = scalars[(size_t)s * VV + tok];
        const float* wp = wvecs + ((size_t)s * VV + tok) * DD;
        w0[s] = wp[lane];
        w1[s] = wp[lane + 64];
    }

    float run0 = 0.f, run1 = 0.f;
    #pragma unroll
    for (int s = 0; s < SS; ++s) {
        float p = fmaf(run0, run0, run1 * run1);
        #pragma unroll
        for (int off = 32; off > 0; off >>= 1)
            p += __shfl_xor(p, off);
        const float denom = fmaxf(sqrtf(p), EPS);  // torch F.normalize semantics
        float* o = ctx_n + ((size_t)s * BB + b) * DD;
        o[lane]      = run0 / denom;
        o[lane + 64] = run1 / denom;
        run0 = fmaf(a[s], w0[s], run0);   // position s contributes to positions > s
        run1 = fmaf(a[s], w1[s], run1);
    }
}

// Kernel 2: out[b,s,v] = SCALE * dot(ctx_n[b,s,:], emb[s,v,:]) / max(||emb[s,v,:]||, eps)
//
// Coalesced redesign (R5 showed per-lane-row global reads cap at ~2.9 TB/s:
// 64 scattered 64B lines per wave-load). Here the global stream is contiguous:
// each block stages a 64-row x 512B emb tile (32 KB) into LDS with float4
// loads where every wave instruction covers 1 KB contiguous. Compute mapping:
// lane = cq*16 + b. Lane holds ctx[b] chunks {4m+cq} in REGISTERS (loaded
// once); wave w sweeps rows 16w..16w+15, reading emb chunks from LDS as
// 16-lane broadcasts (4 distinct addresses per inst, in 4 distinct bank
// groups thanks to the 4m+cq interleave -> conflict-free). Two shfl_xor
// steps (16, 32) fold the 4 chunk-quarters into the full d=128 dot and norm.
__global__ __launch_bounds__(256) void logits_kernel(
    const float* __restrict__ ctx_n,  // [S,B,D] (normalized)
    const float* __restrict__ emb,    // [S,V,D]
    float*       __restrict__ out)    // [B,S,V]
{
    const int s    = blockIdx.y;
    const int v0   = blockIdx.x * TV;
    const int tid  = threadIdx.x;
    const int lane = tid & 63;
    const int w    = tid >> 6;    // wave 0..3
    const int b    = lane & 15;   // batch owned by this lane
    const int cq   = lane >> 4;   // chunk-quarter 0..3

    __shared__ float4 emb_s[TV * NC];   // 2048 float4 = 32 KB

    // ctx chunks for (b, cq): j = 4m + cq. 8 float4 = 32 VGPR, loaded once
    // (384 KB total ctx is L2/L3-resident after first touch).
    float4 cx[CPL];
    const float4* cbase = (const float4*)(ctx_n + ((size_t)s * BB + b) * DD);
    #pragma unroll
    for (int m = 0; m < CPL; ++m)
        cx[m] = cbase[4 * m + cq];

    // Stage emb tile: fully coalesced (1 KB contiguous per wave instruction).
    const float4* gsrc = (const float4*)(emb + ((size_t)s * VV + v0) * DD);
    #pragma unroll
    for (int k = 0; k < (TV * NC) / NT; ++k)   // 8 iterations
        emb_s[tid + k * NT] = gsrc[tid + k * NT];
    __syncthreads();

    const int r0 = w * (TV / 4);   // 16 rows per wave
    #pragma unroll 4
    for (int rr = 0; rr < TV / 4; ++rr) {
        const int r = r0 + rr;
        const float4* erow = &emb_s[r * NC];

        float pd = 0.f, pn = 0.f;
        #pragma unroll
        for (int m = 0; m < CPL; ++m) {
            const float4 e = erow[4 * m + cq];   // 16-lane broadcast, 4 bank groups
            const float4 c = cx[m];
            pd = fmaf(e.x, c.x, pd);
            pd = fmaf(e.y, c.y, pd);
            pd = fmaf(e.z, c.z, pd);
            pd = fmaf(e.w, c.w, pd);
            pn = fmaf(e.x, e.x, pn);
            pn = fmaf(e.y, e.y, pn);
            pn = fmaf(e.z, e.z, pn);
            pn = fmaf(e.w, e.w, pn);
        }
        // fold the 4 chunk-quarters {l, l^16, l^32, l^48} -> full d=128 sums
        pd += __shfl_xor(pd, 16);
        pd += __shfl_xor(pd, 32);
        pn += __shfl_xor(pn, 16);
        pn += __shfl_xor(pn, 32);

        if (cq == 0) {
            const float f = SCALE / fmaxf(sqrtf(pn), EPS);  // F.normalize semantics
            out[((size_t)b * SS + s) * VV + v0 + r] = pd * f;
        }
    }
}

extern "C" void kernel_launch(void* const* d_in, const int* in_sizes, int n_in,
                              void* d_out, int out_size, void* d_ws, size_t ws_size,
                              hipStream_t stream) {
    const int*   tokens  = (const int*)d_in[0];
    const float* scalars = (const float*)d_in[1];
    const float* wvecs   = (const float*)d_in[2];
    const float* emb     = (const float*)d_in[3];
    float*       out     = (float*)d_out;
    float*       ctx_n   = (float*)d_ws;   // S*B*D*4 = 393,216 bytes

    ctx_kernel<<<dim3(BB), dim3(64), 0, stream>>>(tokens, scalars, wvecs, ctx_n);

    dim3 grid(VV / TV, SS);   // (250, 48) = 12000 blocks
    logits_kernel<<<grid, dim3(NT), 0, stream>>>(ctx_n, emb, out);
}